// Round 16
// baseline (148.914 us; speedup 1.0000x reference)
//
#include <hip/hip_runtime.h>

#define NPI 50      // nodes per inner graph
#define EPI 400     // edges per inner graph
#define NPO 125     // nodes per outer graph
#define EPO 1000    // edges per outer graph
#define N_IN 100000
#define N_OUT 2000
#define NB 16       // batch graphs
#define NC 10

typedef _Float16 half_t;
typedef _Float16 f16x8 __attribute__((ext_vector_type(8)));
typedef _Float16 f16x4 __attribute__((ext_vector_type(4)));
typedef float f32x4 __attribute__((ext_vector_type(4)));

#define MFMA(a, b, c) __builtin_amdgcn_mfma_f32_16x16x32_f16(a, b, c, 0, 0, 0)

// LDS-only barrier (r12-proven neutral vs __syncthreads, keeps prefetches live).
__device__ __forceinline__ void lds_barrier() {
    asm volatile("s_waitcnt lgkmcnt(0)" ::: "memory");
    __builtin_amdgcn_s_barrier();
}

// Swizzled LDS helpers. XOR of (row&7) into byte bits 4..6 keeps ds_read_b128
// conflict-free when 16 lanes read 16 consecutive rows.
__device__ __forceinline__ f16x8 lds_ld8(const half_t* base, int row, int k, int strideB) {
    return *(const f16x8*)((const char*)base + row * strideB + ((k * 2) ^ ((row & 7) << 4)));
}
__device__ __forceinline__ void lds_st1(half_t* base, int row, int col, int strideB, float v) {
    *(half_t*)((char*)base + row * strideB + ((col * 2) ^ ((row & 7) << 4))) = (half_t)v;
}
__device__ __forceinline__ void lds_st1h(half_t* base, int row, int col, int strideB, half_t v) {
    *(half_t*)((char*)base + row * strideB + ((col * 2) ^ ((row & 7) << 4))) = v;
}
// b64 store of 4 node-contiguous halfs (col0 multiple of 4): 8B span stays
// contiguous under the XOR-bits-4..6 swizzle.
__device__ __forceinline__ void lds_st4h(half_t* base, int row, int col0, int strideB, f16x4 v) {
    *(f16x4*)((char*)base + row * strideB + ((col0 * 2) ^ ((row & 7) << 4))) = v;
}
// per-wave scratch [16][32] f16, stride 64B, XOR (row&3)<<4
__device__ __forceinline__ f16x8 scr_ld8(const half_t* base, int row, int k) {
    return *(const f16x8*)((const char*)base + row * 64 + ((k * 2) ^ ((row & 3) << 4)));
}
__device__ __forceinline__ void scr_st1(half_t* base, int row, int col, float v) {
    *(half_t*)((char*)base + row * 64 + ((col * 2) ^ ((row & 3) << 4))) = (half_t)v;
}

// ---------------------------------------------------------------------------
// k_pre: blocks 0..383 convert W1..W6 -> transposed f16; blocks 384..399 build
// dense outer adjacency Â_outer [16][128][128] f16 (row-major). [r4-proven]
// ---------------------------------------------------------------------------
__global__ __launch_bounds__(256) void k_pre(
    const float* __restrict__ W1, const float* __restrict__ W2,
    const float* __restrict__ W3, const float* __restrict__ W4,
    const float* __restrict__ W5, const float* __restrict__ W6,
    half_t* __restrict__ WT1, half_t* __restrict__ WT2,
    half_t* __restrict__ WT3, half_t* __restrict__ WT4,
    half_t* __restrict__ WT5, half_t* __restrict__ WT6,
    const float* __restrict__ ew, const int* __restrict__ esrc,
    const int* __restrict__ edst, half_t* __restrict__ Aout)
{
    __shared__ float Af[NPO * NPO];
    __shared__ int cO[NPO], cI[NPO];
    __shared__ float rso[NPO], rsi[NPO];
    const int t = threadIdx.x;

    if (blockIdx.x < 384) {
        int i = blockIdx.x * 256 + t;
        const float* src; half_t* dst; int K;
        if      (i < 8192)  { src = W1; dst = WT1; K = 64; }
        else if (i < 24576) { src = W2; dst = WT2; K = 128; i -= 8192; }
        else if (i < 49152) { src = W3; dst = WT3; K = 192; i -= 24576; }
        else if (i < 65536) { src = W4; dst = WT4; K = 128; i -= 49152; }
        else if (i < 81920) { src = W5; dst = WT5; K = 128; i -= 65536; }
        else                { src = W6; dst = WT6; K = 128; i -= 81920; }
        int c = i & 127, k = i >> 7;
        dst[c * K + k] = (half_t)src[k * 128 + c];
        return;
    }

    const int g = blockIdx.x - 384;
    const int nb = g * NPO, eb = g * EPO;
    for (int i = t; i < NPO * NPO; i += 256) Af[i] = 0.f;
    if (t < NPO) { cO[t] = 0; cI[t] = 0; }
    __syncthreads();
    for (int e = t; e < EPO; e += 256) {
        int s = esrc[eb + e] - nb, d = edst[eb + e] - nb;
        atomicAdd(&Af[d * NPO + s], ew[eb + e]);
        atomicAdd(&cO[s], 1); atomicAdd(&cI[d], 1);
    }
    __syncthreads();
    if (t < NPO) {
        rso[t] = rsqrtf((float)max(cO[t], 1));
        rsi[t] = rsqrtf((float)max(cI[t], 1));
    }
    __syncthreads();
    for (int i = t; i < 128 * 16; i += 256) {
        int d = i >> 4, s0 = (i & 15) * 8;
        f16x8 v;
        #pragma unroll
        for (int j = 0; j < 8; j++) {
            int s = s0 + j;
            float x = (d < NPO && s < NPO) ? Af[d * NPO + s] * rsi[d] * rso[s] : 0.f;
            v[j] = (half_t)x;
        }
        *(f16x8*)&Aout[(size_t)g * 16384 + d * 128 + s0] = v;
    }
}

// ---------------------------------------------------------------------------
// Inner fused, 5-barrier variant [r15-proven] — now at __launch_bounds__(256,7):
// LDS 21504B allows 7 blocks/CU; measured VGPR need is 48 < 512/7=73 cap, so
// no spill risk (r5's spill was ~90 VGPR of live state; this kernel has 48).
// ---------------------------------------------------------------------------
__global__ __launch_bounds__(256, 7) void k_inner(
    const float* __restrict__ X, const float* __restrict__ outfeat,
    const float* __restrict__ ew, const int* __restrict__ esrc,
    const int* __restrict__ edst,
    const half_t* __restrict__ WT1, const float* __restrict__ b1,
    const half_t* __restrict__ WT2, const float* __restrict__ b2,
    half_t* __restrict__ merged)
{
    __shared__ alignas(16) char smem[21504];
    half_t* R2  = (half_t*)smem;             // [128][64] f16 swz s128 (h1T)
    float*  Af  = (float*)smem;              // [64][64] f32, bank-swizzled (alias)
    half_t* scr = (half_t*)(smem + 16384);   // [4 waves][16][32] f16
    float*  pool= (float*)(smem + 20480);    // [128]
    int*    cO  = (int*)(smem + 20992);      // [64]
    int*    cI  = (int*)(smem + 21248);      // [64]

    const int g = blockIdx.x, t = threadIdx.x;
    const int w = t >> 6, l = t & 63, lr = l & 15, lk = l >> 4;
    const int nb = g * NPI, eb = g * EPI;
    half_t* scrw = scr + w * 512;

    // ---- all global prefetches issued at kernel entry ----
    float ofv = (t < 64) ? outfeat[(size_t)g * 64 + t] : 0.f;
    int s0e, d0e; float w0e;
    { int e = eb + t; s0e = esrc[e] - nb; d0e = edst[e] - nb; w0e = ew[e]; }
    int s1e = 0, d1e = 0; float w1e = 0.f;
    const bool e1v = (t + 256 < EPI);
    if (e1v) { int e = eb + t + 256; s1e = esrc[e] - nb; d1e = edst[e] - nb; w1e = ew[e]; }
    // T1 B-fragments direct from X: frag(ft,ks) = X[node=ks*32+lk*8+j][ft*16+lr],
    // shared by all 4 waves (4x redundant L2 reads, zero LDS).
    f16x8 bx[8];
    #pragma unroll
    for (int fi = 0; fi < 4; fi++) {
        #pragma unroll
        for (int ks = 0; ks < 2; ks++) {
            f16x8 v;
            #pragma unroll
            for (int jj = 0; jj < 8; jj++) {
                int n = ks * 32 + lk * 8 + jj;
                int ridx = nb + n; if (ridx > N_IN - 1) ridx = N_IN - 1;
                v[jj] = (half_t)X[(size_t)ridx * 64 + fi * 16 + lr];
            }
            bx[fi * 2 + ks] = v;
        }
    }

    if (t < 64) { cO[t] = 0; cI[t] = 0; }
    if (t >= 64 && t < 192) pool[t - 64] = 0.f;
    {
        const f32x4 z4 = {0.f, 0.f, 0.f, 0.f};
        #pragma unroll
        for (int i = 0; i < 4; i++) *(f32x4*)&Af[(i * 256 + t) * 4] = z4;
    }
    lds_barrier();                                           // B1

    // edge scatter into bank-swizzled Af: element (d,s) at d*64 + (s^((d&7)<<2))
    atomicAdd(&Af[d0e * 64 + (s0e ^ ((d0e & 7) << 2))], w0e);
    atomicAdd(&cO[s0e], 1); atomicAdd(&cI[d0e], 1);
    if (e1v) {
        atomicAdd(&Af[d1e * 64 + (s1e ^ ((d1e & 7) << 2))], w1e);
        atomicAdd(&cO[s1e], 1); atomicAdd(&cI[d1e], 1);
    }
    lds_barrier();                                           // B2

    // ---- build Â A-fragments in registers: row = w*16+lr, ks in {0,1} ----
    f16x8 afr[2];
    {
        const int r = w * 16 + lr;
        const int sw = (r & 7) << 2;
        const float rsi_l = rsqrtf((float)max(cI[r], 1));
        #pragma unroll
        for (int ks = 0; ks < 2; ks++) {
            const int c0 = ks * 32 + lk * 8;
            f32x4 v0 = *(const f32x4*)&Af[r * 64 + (c0 ^ sw)];
            f32x4 v1 = *(const f32x4*)&Af[r * 64 + ((c0 + 4) ^ sw)];
            f16x8 fr;
            #pragma unroll
            for (int j = 0; j < 4; j++)
                fr[j] = (half_t)(v0[j] * rsi_l * rsqrtf((float)max(cO[c0 + j], 1)));
            #pragma unroll
            for (int j = 0; j < 4; j++)
                fr[4 + j] = (half_t)(v1[j] * rsi_l * rsqrtf((float)max(cO[c0 + 4 + j], 1)));
            afr[ks] = fr;
        }
    }
    lds_barrier();                                           // B3 (Af reads done)

    // ---- T1 = Â@X (strip-fused, B from registers) -> H1 = relu(T1@W1+b1) ----
    f32x4 hacc[8] = {};
    #pragma unroll
    for (int kf = 0; kf < 2; kf++) {
        f16x8 wb[8];
        #pragma unroll
        for (int nt = 0; nt < 8; nt++)
            wb[nt] = *(const f16x8*)&WT1[(nt * 16 + lr) * 64 + kf * 32 + lk * 8];
        #pragma unroll
        for (int j = 0; j < 2; j++) {
            const int ft = kf * 2 + j;
            f32x4 tacc = {};
            #pragma unroll
            for (int ks = 0; ks < 2; ks++)
                tacc = MFMA(afr[ks], bx[ft * 2 + ks], tacc);
            #pragma unroll
            for (int q = 0; q < 4; q++) scr_st1(scrw, lk * 4 + q, j * 16 + lr, tacc[q]);
        }
        f16x8 a1 = scr_ld8(scrw, lr, lk * 8);
        #pragma unroll
        for (int nt = 0; nt < 8; nt++) hacc[nt] = MFMA(a1, wb[nt], hacc[nt]);
    }
    // h1T writeback: b64 (4 node-contiguous halfs per store)
    #pragma unroll
    for (int nt = 0; nt < 8; nt++) {
        int c = nt * 16 + lr;
        float bb = b1[c];
        f16x4 hv;
        #pragma unroll
        for (int q = 0; q < 4; q++) hv[q] = (half_t)fmaxf(hacc[nt][q] + bb, 0.f);
        lds_st4h(R2, c, w * 16 + lk * 4, 128, hv);
    }
    lds_barrier();                                           // B4 (h1T visible)

    // ---- T2 = Â@h1 (strip-fused) -> H2 = relu(T2@W2+b2) -> masked pool ----
    f32x4 h2[8] = {};
    #pragma unroll
    for (int kf = 0; kf < 4; kf++) {
        f16x8 wb[8];
        #pragma unroll
        for (int nt = 0; nt < 8; nt++)
            wb[nt] = *(const f16x8*)&WT2[(nt * 16 + lr) * 128 + kf * 32 + lk * 8];
        #pragma unroll
        for (int j = 0; j < 2; j++) {
            const int ft = kf * 2 + j;
            f32x4 tacc = {};
            #pragma unroll
            for (int ks = 0; ks < 2; ks++) {
                f16x8 b = lds_ld8(R2, ft * 16 + lr, ks * 32 + lk * 8, 128);
                tacc = MFMA(afr[ks], b, tacc);
            }
            #pragma unroll
            for (int q = 0; q < 4; q++) scr_st1(scrw, lk * 4 + q, j * 16 + lr, tacc[q]);
        }
        f16x8 a1 = scr_ld8(scrw, lr, lk * 8);
        #pragma unroll
        for (int nt = 0; nt < 8; nt++) h2[nt] = MFMA(a1, wb[nt], h2[nt]);
    }
    #pragma unroll
    for (int nt = 0; nt < 8; nt++) {
        int c = nt * 16 + lr;
        float bb = b2[c];
        float ps = 0.f;
        #pragma unroll
        for (int q = 0; q < 4; q++) {
            int m = w * 16 + lk * 4 + q;
            float v = fmaxf(h2[nt][q] + bb, 0.f);
            ps += (m < NPI) ? v : 0.f;
        }
        ps += __shfl_xor(ps, 16);
        ps += __shfl_xor(ps, 32);
        if (lk == 0) atomicAdd(&pool[c], ps);
    }
    lds_barrier();                                           // B5
    if (t < 64) merged[(size_t)g * 192 + t] = (half_t)ofv;
    else if (t < 192) merged[(size_t)g * 192 + t] = (half_t)(pool[t - 64] * (1.f / NPI));
}

// ---------------------------------------------------------------------------
// Outer fused @1024 threads [r9/r10-proven]: Â in registers, WT register-
// prefetch, early stage loads, parallel classifier.
// ---------------------------------------------------------------------------
template <int FIN, bool STAGE, bool LAST>
__device__ __forceinline__ void outer_layer(
    const f16x8* afr, const half_t* __restrict__ mg,
    const half_t* __restrict__ WT, const float* __restrict__ bias,
    half_t* bufP, half_t* bufQ, float* pool,
    int wr, int wc, int lr, int lk, int t)
{
    f32x4 hacc[4] = {};
    constexpr int NCH = FIN / 64;
    f16x8 hv[NCH];
    if constexpr (STAGE) {
        const int s = t >> 3, fo = (t & 7) * 8;
        #pragma unroll
        for (int ch = 0; ch < NCH; ch++) {
            f16x8 z = {};
            hv[ch] = (s < NPO) ? *(const f16x8*)&mg[(size_t)s * 192 + ch * 64 + fo] : z;
        }
    }
    #pragma unroll
    for (int ch = 0; ch < NCH; ch++) {
        f16x8 wtb[8];
        #pragma unroll
        for (int ks2 = 0; ks2 < 2; ks2++)
            #pragma unroll
            for (int nt = 0; nt < 4; nt++)
                wtb[ks2 * 4 + nt] = *(const f16x8*)&WT[
                    (size_t)(wc * 64 + nt * 16 + lr) * FIN + ch * 64 + ks2 * 32 + lk * 8];
        if constexpr (STAGE) {
            const int s = t >> 3, fo = (t & 7) * 8;
            #pragma unroll
            for (int j = 0; j < 8; j++) lds_st1h(bufP, fo + j, s, 256, hv[ch][j]);
            lds_barrier();
        }
        const int rb = STAGE ? 0 : ch * 64;
        f32x4 tacc[2] = {};
        #pragma unroll
        for (int ks = 0; ks < 4; ks++) {
            #pragma unroll
            for (int nt = 0; nt < 2; nt++) {
                f16x8 b = lds_ld8(bufP, rb + wc * 32 + nt * 16 + lr, ks * 32 + lk * 8, 256);
                tacc[nt] = MFMA(afr[ks], b, tacc[nt]);
            }
        }
        #pragma unroll
        for (int nt = 0; nt < 2; nt++)
            #pragma unroll
            for (int q = 0; q < 4; q++)
                lds_st1(bufQ, wr * 16 + lk * 4 + q, wc * 32 + nt * 16 + lr, 128,
                        tacc[nt][q]);
        lds_barrier();
        #pragma unroll
        for (int ks2 = 0; ks2 < 2; ks2++) {
            f16x8 a1 = lds_ld8(bufQ, wr * 16 + lr, ks2 * 32 + lk * 8, 128);
            #pragma unroll
            for (int nt = 0; nt < 4; nt++)
                hacc[nt] = MFMA(a1, wtb[ks2 * 4 + nt], hacc[nt]);
        }
        lds_barrier();
    }
    if constexpr (!LAST) {
        #pragma unroll
        for (int nt = 0; nt < 4; nt++) {
            int c = wc * 64 + nt * 16 + lr;
            float bb = bias[c];
            #pragma unroll
            for (int q = 0; q < 4; q++)
                lds_st1(bufP, c, wr * 16 + lk * 4 + q, 256, fmaxf(hacc[nt][q] + bb, 0.f));
        }
        lds_barrier();
    } else {
        #pragma unroll
        for (int nt = 0; nt < 4; nt++) {
            int c = wc * 64 + nt * 16 + lr;
            float bb = bias[c];
            float ps = 0.f;
            #pragma unroll
            for (int q = 0; q < 4; q++) {
                int d = wr * 16 + lk * 4 + q;
                float v = fmaxf(hacc[nt][q] + bb, 0.f);
                ps += (d < NPO) ? v : 0.f;
            }
            ps += __shfl_xor(ps, 16);
            ps += __shfl_xor(ps, 32);
            if (lk == 0) atomicAdd(&pool[c], ps);
        }
        lds_barrier();
    }
}

__global__ __launch_bounds__(1024) void k_outer(
    const half_t* __restrict__ Aout, const half_t* __restrict__ merged,
    const half_t* __restrict__ WT3, const float* __restrict__ b3,
    const half_t* __restrict__ WT4, const float* __restrict__ b4,
    const half_t* __restrict__ WT5, const float* __restrict__ b5,
    const half_t* __restrict__ WT6, const float* __restrict__ b6,
    const float* __restrict__ Wc, const float* __restrict__ bc,
    float* __restrict__ out)
{
    __shared__ alignas(16) char smem[49704];
    half_t* bufP = (half_t*)smem;             // [128][256B] swz (h^T)
    half_t* bufQ = (half_t*)(smem + 32768);   // [128][128B] swz (T chunk)
    float*  pool = (float*)(smem + 49152);    // [128]
    float*  cls  = (float*)(smem + 49664);    // [10]

    const int g = blockIdx.x, t = threadIdx.x;
    const int w = t >> 6, l = t & 63, lr = l & 15, lk = l >> 4;
    const int wr = w & 7, wc = w >> 3;
    const half_t* mg = merged + (size_t)g * NPO * 192;

    f16x8 afr[4];
    #pragma unroll
    for (int ks = 0; ks < 4; ks++)
        afr[ks] = *(const f16x8*)&Aout[(size_t)g * 16384
                                       + (wr * 16 + lr) * 128 + ks * 32 + lk * 8];
    if (t < 128) pool[t] = 0.f;
    if (t >= 128 && t < 128 + NC) cls[t - 128] = 0.f;
    lds_barrier();

    outer_layer<192, true,  false>(afr, mg, WT3, b3, bufP, bufQ, pool, wr, wc, lr, lk, t);
    outer_layer<128, false, false>(afr, nullptr, WT4, b4, bufP, bufQ, pool, wr, wc, lr, lk, t);
    outer_layer<128, false, false>(afr, nullptr, WT5, b5, bufP, bufQ, pool, wr, wc, lr, lk, t);
    outer_layer<128, false, true >(afr, nullptr, WT6, b6, bufP, bufQ, pool, wr, wc, lr, lk, t);

    if (t < 128) {
        float val = pool[t] * (1.f / NPO);
        float p[NC];
        #pragma unroll
        for (int c = 0; c < NC; c++) p[c] = val * Wc[t * NC + c];
        #pragma unroll
        for (int off = 32; off >= 1; off >>= 1)
            #pragma unroll
            for (int c = 0; c < NC; c++) p[c] += __shfl_xor(p[c], off);
        if ((t & 63) == 0)
            #pragma unroll
            for (int c = 0; c < NC; c++) atomicAdd(&cls[c], p[c]);
    }
    lds_barrier();
    if (t < NC) out[g * NC + t] = cls[t] + bc[t];
}

extern "C" void kernel_launch(void* const* d_in, const int* in_sizes, int n_in,
                              void* d_out, int out_size, void* d_ws, size_t ws_size,
                              hipStream_t stream)
{
    const float* X       = (const float*)d_in[0];
    const float* outfeat = (const float*)d_in[1];
    const float* iew     = (const float*)d_in[2];
    const float* oew     = (const float*)d_in[3];
    const float* W1 = (const float*)d_in[4];  const float* b1 = (const float*)d_in[5];
    const float* W2 = (const float*)d_in[6];  const float* b2 = (const float*)d_in[7];
    const float* W3 = (const float*)d_in[8];  const float* b3 = (const float*)d_in[9];
    const float* W4 = (const float*)d_in[10]; const float* b4 = (const float*)d_in[11];
    const float* W5 = (const float*)d_in[12]; const float* b5 = (const float*)d_in[13];
    const float* W6 = (const float*)d_in[14]; const float* b6 = (const float*)d_in[15];
    const float* Wc = (const float*)d_in[16]; const float* bc = (const float*)d_in[17];
    const int* isrc = (const int*)d_in[18];   const int* idst = (const int*)d_in[19];
    const int* osrc = (const int*)d_in[20];   const int* odst = (const int*)d_in[21];

    char* base = (char*)d_ws;
    half_t* WT1 = (half_t*)(base + 0);        // [128][64]
    half_t* WT2 = (half_t*)(base + 16384);    // [128][128]
    half_t* WT3 = (half_t*)(base + 49152);    // [128][192]
    half_t* WT4 = (half_t*)(base + 98304);    // [128][128]
    half_t* WT5 = (half_t*)(base + 131072);   // [128][128]
    half_t* WT6 = (half_t*)(base + 163840);   // [128][128]
    half_t* AoutG  = (half_t*)(base + 196608);   // [16][128][128]
    half_t* merged = (half_t*)(base + 720896);   // [2000][192]

    k_pre<<<400, 256, 0, stream>>>(W1, W2, W3, W4, W5, W6,
                                   WT1, WT2, WT3, WT4, WT5, WT6,
                                   oew, osrc, odst, AoutG);
    k_inner<<<N_OUT, 256, 0, stream>>>(X, outfeat, iew, isrc, idst,
                                       WT1, b1, WT2, b2, merged);
    k_outer<<<NB, 1024, 0, stream>>>(AoutG, merged, WT3, b3, WT4, b4,
                                     WT5, b5, WT6, b6, Wc, bc, (float*)d_out);
}

// Round 17
// 139.986 us; speedup vs baseline: 1.0638x; 1.0638x over previous
//
#include <hip/hip_runtime.h>

#define NPI 50      // nodes per inner graph
#define EPI 400     // edges per inner graph
#define NPO 125     // nodes per outer graph
#define EPO 1000    // edges per outer graph
#define N_IN 100000
#define N_OUT 2000
#define NB 16       // batch graphs
#define NC 10

typedef _Float16 half_t;
typedef _Float16 f16x8 __attribute__((ext_vector_type(8)));
typedef _Float16 f16x4 __attribute__((ext_vector_type(4)));
typedef float f32x4 __attribute__((ext_vector_type(4)));

#define MFMA(a, b, c) __builtin_amdgcn_mfma_f32_16x16x32_f16(a, b, c, 0, 0, 0)

// LDS-only barrier (r12-proven neutral vs __syncthreads, keeps prefetches live).
__device__ __forceinline__ void lds_barrier() {
    asm volatile("s_waitcnt lgkmcnt(0)" ::: "memory");
    __builtin_amdgcn_s_barrier();
}

// Swizzled LDS helpers. XOR of (row&7) into byte bits 4..6 keeps ds_read_b128
// conflict-free when 16 lanes read 16 consecutive rows.
__device__ __forceinline__ f16x8 lds_ld8(const half_t* base, int row, int k, int strideB) {
    return *(const f16x8*)((const char*)base + row * strideB + ((k * 2) ^ ((row & 7) << 4)));
}
__device__ __forceinline__ void lds_st1(half_t* base, int row, int col, int strideB, float v) {
    *(half_t*)((char*)base + row * strideB + ((col * 2) ^ ((row & 7) << 4))) = (half_t)v;
}
__device__ __forceinline__ void lds_st1h(half_t* base, int row, int col, int strideB, half_t v) {
    *(half_t*)((char*)base + row * strideB + ((col * 2) ^ ((row & 7) << 4))) = v;
}
// b64 store of 4 node-contiguous halfs (col0 multiple of 4): 8B span stays
// contiguous under the XOR-bits-4..6 swizzle.
__device__ __forceinline__ void lds_st4h(half_t* base, int row, int col0, int strideB, f16x4 v) {
    *(f16x4*)((char*)base + row * strideB + ((col0 * 2) ^ ((row & 7) << 4))) = v;
}
// per-wave scratch [16][32] f16, stride 64B, XOR (row&3)<<4
__device__ __forceinline__ f16x8 scr_ld8(const half_t* base, int row, int k) {
    return *(const f16x8*)((const char*)base + row * 64 + ((k * 2) ^ ((row & 3) << 4)));
}
__device__ __forceinline__ void scr_st1(half_t* base, int row, int col, float v) {
    *(half_t*)((char*)base + row * 64 + ((col * 2) ^ ((row & 3) << 4))) = (half_t)v;
}

// ---------------------------------------------------------------------------
// k_pre: blocks 0..383 convert W1..W6 -> transposed f16; blocks 384..399 build
// dense outer adjacency Â_outer [16][128][128] f16 (row-major). [r4-proven]
// ---------------------------------------------------------------------------
__global__ __launch_bounds__(256) void k_pre(
    const float* __restrict__ W1, const float* __restrict__ W2,
    const float* __restrict__ W3, const float* __restrict__ W4,
    const float* __restrict__ W5, const float* __restrict__ W6,
    half_t* __restrict__ WT1, half_t* __restrict__ WT2,
    half_t* __restrict__ WT3, half_t* __restrict__ WT4,
    half_t* __restrict__ WT5, half_t* __restrict__ WT6,
    const float* __restrict__ ew, const int* __restrict__ esrc,
    const int* __restrict__ edst, half_t* __restrict__ Aout)
{
    __shared__ float Af[NPO * NPO];
    __shared__ int cO[NPO], cI[NPO];
    __shared__ float rso[NPO], rsi[NPO];
    const int t = threadIdx.x;

    if (blockIdx.x < 384) {
        int i = blockIdx.x * 256 + t;
        const float* src; half_t* dst; int K;
        if      (i < 8192)  { src = W1; dst = WT1; K = 64; }
        else if (i < 24576) { src = W2; dst = WT2; K = 128; i -= 8192; }
        else if (i < 49152) { src = W3; dst = WT3; K = 192; i -= 24576; }
        else if (i < 65536) { src = W4; dst = WT4; K = 128; i -= 49152; }
        else if (i < 81920) { src = W5; dst = WT5; K = 128; i -= 65536; }
        else                { src = W6; dst = WT6; K = 128; i -= 81920; }
        int c = i & 127, k = i >> 7;
        dst[c * K + k] = (half_t)src[k * 128 + c];
        return;
    }

    const int g = blockIdx.x - 384;
    const int nb = g * NPO, eb = g * EPO;
    for (int i = t; i < NPO * NPO; i += 256) Af[i] = 0.f;
    if (t < NPO) { cO[t] = 0; cI[t] = 0; }
    __syncthreads();
    for (int e = t; e < EPO; e += 256) {
        int s = esrc[eb + e] - nb, d = edst[eb + e] - nb;
        atomicAdd(&Af[d * NPO + s], ew[eb + e]);
        atomicAdd(&cO[s], 1); atomicAdd(&cI[d], 1);
    }
    __syncthreads();
    if (t < NPO) {
        rso[t] = rsqrtf((float)max(cO[t], 1));
        rsi[t] = rsqrtf((float)max(cI[t], 1));
    }
    __syncthreads();
    for (int i = t; i < 128 * 16; i += 256) {
        int d = i >> 4, s0 = (i & 15) * 8;
        f16x8 v;
        #pragma unroll
        for (int j = 0; j < 8; j++) {
            int s = s0 + j;
            float x = (d < NPO && s < NPO) ? Af[d * NPO + s] * rsi[d] * rso[s] : 0.f;
            v[j] = (half_t)x;
        }
        *(f16x8*)&Aout[(size_t)g * 16384 + d * 128 + s0] = v;
    }
}

// ---------------------------------------------------------------------------
// Inner fused, 5-barrier variant [r15-proven] at __launch_bounds__(256,6):
// unified VGPR+AGPR pressure ~80 (VGPR 48 + ~32 acc); (256,7) cap 73 spilled
// (r16), (256,5) cap 102 fits at 5 blocks/CU; (256,6) cap 85 targets 6.
// ---------------------------------------------------------------------------
__global__ __launch_bounds__(256, 6) void k_inner(
    const float* __restrict__ X, const float* __restrict__ outfeat,
    const float* __restrict__ ew, const int* __restrict__ esrc,
    const int* __restrict__ edst,
    const half_t* __restrict__ WT1, const float* __restrict__ b1,
    const half_t* __restrict__ WT2, const float* __restrict__ b2,
    half_t* __restrict__ merged)
{
    __shared__ alignas(16) char smem[21504];
    half_t* R2  = (half_t*)smem;             // [128][64] f16 swz s128 (h1T)
    float*  Af  = (float*)smem;              // [64][64] f32, bank-swizzled (alias)
    half_t* scr = (half_t*)(smem + 16384);   // [4 waves][16][32] f16
    float*  pool= (float*)(smem + 20480);    // [128]
    int*    cO  = (int*)(smem + 20992);      // [64]
    int*    cI  = (int*)(smem + 21248);      // [64]

    const int g = blockIdx.x, t = threadIdx.x;
    const int w = t >> 6, l = t & 63, lr = l & 15, lk = l >> 4;
    const int nb = g * NPI, eb = g * EPI;
    half_t* scrw = scr + w * 512;

    // ---- all global prefetches issued at kernel entry ----
    float ofv = (t < 64) ? outfeat[(size_t)g * 64 + t] : 0.f;
    int s0e, d0e; float w0e;
    { int e = eb + t; s0e = esrc[e] - nb; d0e = edst[e] - nb; w0e = ew[e]; }
    int s1e = 0, d1e = 0; float w1e = 0.f;
    const bool e1v = (t + 256 < EPI);
    if (e1v) { int e = eb + t + 256; s1e = esrc[e] - nb; d1e = edst[e] - nb; w1e = ew[e]; }
    // T1 B-fragments direct from X: frag(ft,ks) = X[node=ks*32+lk*8+j][ft*16+lr],
    // shared by all 4 waves (4x redundant L2 reads, zero LDS).
    f16x8 bx[8];
    #pragma unroll
    for (int fi = 0; fi < 4; fi++) {
        #pragma unroll
        for (int ks = 0; ks < 2; ks++) {
            f16x8 v;
            #pragma unroll
            for (int jj = 0; jj < 8; jj++) {
                int n = ks * 32 + lk * 8 + jj;
                int ridx = nb + n; if (ridx > N_IN - 1) ridx = N_IN - 1;
                v[jj] = (half_t)X[(size_t)ridx * 64 + fi * 16 + lr];
            }
            bx[fi * 2 + ks] = v;
        }
    }

    if (t < 64) { cO[t] = 0; cI[t] = 0; }
    if (t >= 64 && t < 192) pool[t - 64] = 0.f;
    {
        const f32x4 z4 = {0.f, 0.f, 0.f, 0.f};
        #pragma unroll
        for (int i = 0; i < 4; i++) *(f32x4*)&Af[(i * 256 + t) * 4] = z4;
    }
    lds_barrier();                                           // B1

    // edge scatter into bank-swizzled Af: element (d,s) at d*64 + (s^((d&7)<<2))
    atomicAdd(&Af[d0e * 64 + (s0e ^ ((d0e & 7) << 2))], w0e);
    atomicAdd(&cO[s0e], 1); atomicAdd(&cI[d0e], 1);
    if (e1v) {
        atomicAdd(&Af[d1e * 64 + (s1e ^ ((d1e & 7) << 2))], w1e);
        atomicAdd(&cO[s1e], 1); atomicAdd(&cI[d1e], 1);
    }
    lds_barrier();                                           // B2

    // ---- build Â A-fragments in registers: row = w*16+lr, ks in {0,1} ----
    f16x8 afr[2];
    {
        const int r = w * 16 + lr;
        const int sw = (r & 7) << 2;
        const float rsi_l = rsqrtf((float)max(cI[r], 1));
        #pragma unroll
        for (int ks = 0; ks < 2; ks++) {
            const int c0 = ks * 32 + lk * 8;
            f32x4 v0 = *(const f32x4*)&Af[r * 64 + (c0 ^ sw)];
            f32x4 v1 = *(const f32x4*)&Af[r * 64 + ((c0 + 4) ^ sw)];
            f16x8 fr;
            #pragma unroll
            for (int j = 0; j < 4; j++)
                fr[j] = (half_t)(v0[j] * rsi_l * rsqrtf((float)max(cO[c0 + j], 1)));
            #pragma unroll
            for (int j = 0; j < 4; j++)
                fr[4 + j] = (half_t)(v1[j] * rsi_l * rsqrtf((float)max(cO[c0 + 4 + j], 1)));
            afr[ks] = fr;
        }
    }
    lds_barrier();                                           // B3 (Af reads done)

    // ---- T1 = Â@X (strip-fused, B from registers) -> H1 = relu(T1@W1+b1) ----
    f32x4 hacc[8] = {};
    #pragma unroll
    for (int kf = 0; kf < 2; kf++) {
        f16x8 wb[8];
        #pragma unroll
        for (int nt = 0; nt < 8; nt++)
            wb[nt] = *(const f16x8*)&WT1[(nt * 16 + lr) * 64 + kf * 32 + lk * 8];
        #pragma unroll
        for (int j = 0; j < 2; j++) {
            const int ft = kf * 2 + j;
            f32x4 tacc = {};
            #pragma unroll
            for (int ks = 0; ks < 2; ks++)
                tacc = MFMA(afr[ks], bx[ft * 2 + ks], tacc);
            #pragma unroll
            for (int q = 0; q < 4; q++) scr_st1(scrw, lk * 4 + q, j * 16 + lr, tacc[q]);
        }
        f16x8 a1 = scr_ld8(scrw, lr, lk * 8);
        #pragma unroll
        for (int nt = 0; nt < 8; nt++) hacc[nt] = MFMA(a1, wb[nt], hacc[nt]);
    }
    // h1T writeback: b64 (4 node-contiguous halfs per store)
    #pragma unroll
    for (int nt = 0; nt < 8; nt++) {
        int c = nt * 16 + lr;
        float bb = b1[c];
        f16x4 hv;
        #pragma unroll
        for (int q = 0; q < 4; q++) hv[q] = (half_t)fmaxf(hacc[nt][q] + bb, 0.f);
        lds_st4h(R2, c, w * 16 + lk * 4, 128, hv);
    }
    lds_barrier();                                           // B4 (h1T visible)

    // ---- T2 = Â@h1 (strip-fused) -> H2 = relu(T2@W2+b2) -> masked pool ----
    f32x4 h2[8] = {};
    #pragma unroll
    for (int kf = 0; kf < 4; kf++) {
        f16x8 wb[8];
        #pragma unroll
        for (int nt = 0; nt < 8; nt++)
            wb[nt] = *(const f16x8*)&WT2[(nt * 16 + lr) * 128 + kf * 32 + lk * 8];
        #pragma unroll
        for (int j = 0; j < 2; j++) {
            const int ft = kf * 2 + j;
            f32x4 tacc = {};
            #pragma unroll
            for (int ks = 0; ks < 2; ks++) {
                f16x8 b = lds_ld8(R2, ft * 16 + lr, ks * 32 + lk * 8, 128);
                tacc = MFMA(afr[ks], b, tacc);
            }
            #pragma unroll
            for (int q = 0; q < 4; q++) scr_st1(scrw, lk * 4 + q, j * 16 + lr, tacc[q]);
        }
        f16x8 a1 = scr_ld8(scrw, lr, lk * 8);
        #pragma unroll
        for (int nt = 0; nt < 8; nt++) h2[nt] = MFMA(a1, wb[nt], h2[nt]);
    }
    #pragma unroll
    for (int nt = 0; nt < 8; nt++) {
        int c = nt * 16 + lr;
        float bb = b2[c];
        float ps = 0.f;
        #pragma unroll
        for (int q = 0; q < 4; q++) {
            int m = w * 16 + lk * 4 + q;
            float v = fmaxf(h2[nt][q] + bb, 0.f);
            ps += (m < NPI) ? v : 0.f;
        }
        ps += __shfl_xor(ps, 16);
        ps += __shfl_xor(ps, 32);
        if (lk == 0) atomicAdd(&pool[c], ps);
    }
    lds_barrier();                                           // B5
    if (t < 64) merged[(size_t)g * 192 + t] = (half_t)ofv;
    else if (t < 192) merged[(size_t)g * 192 + t] = (half_t)(pool[t - 64] * (1.f / NPI));
}

// ---------------------------------------------------------------------------
// Outer fused @1024 threads [r9/r10-proven]: Â in registers, WT register-
// prefetch, early stage loads, parallel classifier.
// ---------------------------------------------------------------------------
template <int FIN, bool STAGE, bool LAST>
__device__ __forceinline__ void outer_layer(
    const f16x8* afr, const half_t* __restrict__ mg,
    const half_t* __restrict__ WT, const float* __restrict__ bias,
    half_t* bufP, half_t* bufQ, float* pool,
    int wr, int wc, int lr, int lk, int t)
{
    f32x4 hacc[4] = {};
    constexpr int NCH = FIN / 64;
    f16x8 hv[NCH];
    if constexpr (STAGE) {
        const int s = t >> 3, fo = (t & 7) * 8;
        #pragma unroll
        for (int ch = 0; ch < NCH; ch++) {
            f16x8 z = {};
            hv[ch] = (s < NPO) ? *(const f16x8*)&mg[(size_t)s * 192 + ch * 64 + fo] : z;
        }
    }
    #pragma unroll
    for (int ch = 0; ch < NCH; ch++) {
        f16x8 wtb[8];
        #pragma unroll
        for (int ks2 = 0; ks2 < 2; ks2++)
            #pragma unroll
            for (int nt = 0; nt < 4; nt++)
                wtb[ks2 * 4 + nt] = *(const f16x8*)&WT[
                    (size_t)(wc * 64 + nt * 16 + lr) * FIN + ch * 64 + ks2 * 32 + lk * 8];
        if constexpr (STAGE) {
            const int s = t >> 3, fo = (t & 7) * 8;
            #pragma unroll
            for (int j = 0; j < 8; j++) lds_st1h(bufP, fo + j, s, 256, hv[ch][j]);
            lds_barrier();
        }
        const int rb = STAGE ? 0 : ch * 64;
        f32x4 tacc[2] = {};
        #pragma unroll
        for (int ks = 0; ks < 4; ks++) {
            #pragma unroll
            for (int nt = 0; nt < 2; nt++) {
                f16x8 b = lds_ld8(bufP, rb + wc * 32 + nt * 16 + lr, ks * 32 + lk * 8, 256);
                tacc[nt] = MFMA(afr[ks], b, tacc[nt]);
            }
        }
        #pragma unroll
        for (int nt = 0; nt < 2; nt++)
            #pragma unroll
            for (int q = 0; q < 4; q++)
                lds_st1(bufQ, wr * 16 + lk * 4 + q, wc * 32 + nt * 16 + lr, 128,
                        tacc[nt][q]);
        lds_barrier();
        #pragma unroll
        for (int ks2 = 0; ks2 < 2; ks2++) {
            f16x8 a1 = lds_ld8(bufQ, wr * 16 + lr, ks2 * 32 + lk * 8, 128);
            #pragma unroll
            for (int nt = 0; nt < 4; nt++)
                hacc[nt] = MFMA(a1, wtb[ks2 * 4 + nt], hacc[nt]);
        }
        lds_barrier();
    }
    if constexpr (!LAST) {
        #pragma unroll
        for (int nt = 0; nt < 4; nt++) {
            int c = wc * 64 + nt * 16 + lr;
            float bb = bias[c];
            #pragma unroll
            for (int q = 0; q < 4; q++)
                lds_st1(bufP, c, wr * 16 + lk * 4 + q, 256, fmaxf(hacc[nt][q] + bb, 0.f));
        }
        lds_barrier();
    } else {
        #pragma unroll
        for (int nt = 0; nt < 4; nt++) {
            int c = wc * 64 + nt * 16 + lr;
            float bb = bias[c];
            float ps = 0.f;
            #pragma unroll
            for (int q = 0; q < 4; q++) {
                int d = wr * 16 + lk * 4 + q;
                float v = fmaxf(hacc[nt][q] + bb, 0.f);
                ps += (d < NPO) ? v : 0.f;
            }
            ps += __shfl_xor(ps, 16);
            ps += __shfl_xor(ps, 32);
            if (lk == 0) atomicAdd(&pool[c], ps);
        }
        lds_barrier();
    }
}

__global__ __launch_bounds__(1024) void k_outer(
    const half_t* __restrict__ Aout, const half_t* __restrict__ merged,
    const half_t* __restrict__ WT3, const float* __restrict__ b3,
    const half_t* __restrict__ WT4, const float* __restrict__ b4,
    const half_t* __restrict__ WT5, const float* __restrict__ b5,
    const half_t* __restrict__ WT6, const float* __restrict__ b6,
    const float* __restrict__ Wc, const float* __restrict__ bc,
    float* __restrict__ out)
{
    __shared__ alignas(16) char smem[49704];
    half_t* bufP = (half_t*)smem;             // [128][256B] swz (h^T)
    half_t* bufQ = (half_t*)(smem + 32768);   // [128][128B] swz (T chunk)
    float*  pool = (float*)(smem + 49152);    // [128]
    float*  cls  = (float*)(smem + 49664);    // [10]

    const int g = blockIdx.x, t = threadIdx.x;
    const int w = t >> 6, l = t & 63, lr = l & 15, lk = l >> 4;
    const int wr = w & 7, wc = w >> 3;
    const half_t* mg = merged + (size_t)g * NPO * 192;

    f16x8 afr[4];
    #pragma unroll
    for (int ks = 0; ks < 4; ks++)
        afr[ks] = *(const f16x8*)&Aout[(size_t)g * 16384
                                       + (wr * 16 + lr) * 128 + ks * 32 + lk * 8];
    if (t < 128) pool[t] = 0.f;
    if (t >= 128 && t < 128 + NC) cls[t - 128] = 0.f;
    lds_barrier();

    outer_layer<192, true,  false>(afr, mg, WT3, b3, bufP, bufQ, pool, wr, wc, lr, lk, t);
    outer_layer<128, false, false>(afr, nullptr, WT4, b4, bufP, bufQ, pool, wr, wc, lr, lk, t);
    outer_layer<128, false, false>(afr, nullptr, WT5, b5, bufP, bufQ, pool, wr, wc, lr, lk, t);
    outer_layer<128, false, true >(afr, nullptr, WT6, b6, bufP, bufQ, pool, wr, wc, lr, lk, t);

    if (t < 128) {
        float val = pool[t] * (1.f / NPO);
        float p[NC];
        #pragma unroll
        for (int c = 0; c < NC; c++) p[c] = val * Wc[t * NC + c];
        #pragma unroll
        for (int off = 32; off >= 1; off >>= 1)
            #pragma unroll
            for (int c = 0; c < NC; c++) p[c] += __shfl_xor(p[c], off);
        if ((t & 63) == 0)
            #pragma unroll
            for (int c = 0; c < NC; c++) atomicAdd(&cls[c], p[c]);
    }
    lds_barrier();
    if (t < NC) out[g * NC + t] = cls[t] + bc[t];
}

extern "C" void kernel_launch(void* const* d_in, const int* in_sizes, int n_in,
                              void* d_out, int out_size, void* d_ws, size_t ws_size,
                              hipStream_t stream)
{
    const float* X       = (const float*)d_in[0];
    const float* outfeat = (const float*)d_in[1];
    const float* iew     = (const float*)d_in[2];
    const float* oew     = (const float*)d_in[3];
    const float* W1 = (const float*)d_in[4];  const float* b1 = (const float*)d_in[5];
    const float* W2 = (const float*)d_in[6];  const float* b2 = (const float*)d_in[7];
    const float* W3 = (const float*)d_in[8];  const float* b3 = (const float*)d_in[9];
    const float* W4 = (const float*)d_in[10]; const float* b4 = (const float*)d_in[11];
    const float* W5 = (const float*)d_in[12]; const float* b5 = (const float*)d_in[13];
    const float* W6 = (const float*)d_in[14]; const float* b6 = (const float*)d_in[15];
    const float* Wc = (const float*)d_in[16]; const float* bc = (const float*)d_in[17];
    const int* isrc = (const int*)d_in[18];   const int* idst = (const int*)d_in[19];
    const int* osrc = (const int*)d_in[20];   const int* odst = (const int*)d_in[21];

    char* base = (char*)d_ws;
    half_t* WT1 = (half_t*)(base + 0);        // [128][64]
    half_t* WT2 = (half_t*)(base + 16384);    // [128][128]
    half_t* WT3 = (half_t*)(base + 49152);    // [128][192]
    half_t* WT4 = (half_t*)(base + 98304);    // [128][128]
    half_t* WT5 = (half_t*)(base + 131072);   // [128][128]
    half_t* WT6 = (half_t*)(base + 163840);   // [128][128]
    half_t* AoutG  = (half_t*)(base + 196608);   // [16][128][128]
    half_t* merged = (half_t*)(base + 720896);   // [2000][192]

    k_pre<<<400, 256, 0, stream>>>(W1, W2, W3, W4, W5, W6,
                                   WT1, WT2, WT3, WT4, WT5, WT6,
                                   oew, osrc, odst, AoutG);
    k_inner<<<N_OUT, 256, 0, stream>>>(X, outfeat, iew, isrc, idst,
                                       WT1, b1, WT2, b2, merged);
    k_outer<<<NB, 1024, 0, stream>>>(AoutG, merged, WT3, b3, WT4, b4,
                                     WT5, b5, WT6, b6, Wc, bc, (float*)d_out);
}

// Round 18
// 120.329 us; speedup vs baseline: 1.2376x; 1.1634x over previous
//
#include <hip/hip_runtime.h>

#define NPI 50      // nodes per inner graph
#define EPI 400     // edges per inner graph
#define NPO 125     // nodes per outer graph
#define EPO 1000    // edges per outer graph
#define N_IN 100000
#define N_OUT 2000
#define NB 16       // batch graphs
#define NC 10

typedef _Float16 half_t;
typedef _Float16 f16x8 __attribute__((ext_vector_type(8)));
typedef _Float16 f16x4 __attribute__((ext_vector_type(4)));
typedef float f32x4 __attribute__((ext_vector_type(4)));

#define MFMA(a, b, c) __builtin_amdgcn_mfma_f32_16x16x32_f16(a, b, c, 0, 0, 0)

// LDS-only barrier (r12-proven neutral vs __syncthreads, keeps prefetches live).
__device__ __forceinline__ void lds_barrier() {
    asm volatile("s_waitcnt lgkmcnt(0)" ::: "memory");
    __builtin_amdgcn_s_barrier();
}

// Swizzled LDS helpers. XOR of (row&7) into byte bits 4..6 keeps ds_read_b128
// conflict-free when 16 lanes read 16 consecutive rows.
__device__ __forceinline__ f16x8 lds_ld8(const half_t* base, int row, int k, int strideB) {
    return *(const f16x8*)((const char*)base + row * strideB + ((k * 2) ^ ((row & 7) << 4)));
}
__device__ __forceinline__ void lds_st1(half_t* base, int row, int col, int strideB, float v) {
    *(half_t*)((char*)base + row * strideB + ((col * 2) ^ ((row & 7) << 4))) = (half_t)v;
}
__device__ __forceinline__ void lds_st1h(half_t* base, int row, int col, int strideB, half_t v) {
    *(half_t*)((char*)base + row * strideB + ((col * 2) ^ ((row & 7) << 4))) = v;
}
// b64 store of 4 node-contiguous halfs (col0 multiple of 4).
__device__ __forceinline__ void lds_st4h(half_t* base, int row, int col0, int strideB, f16x4 v) {
    *(f16x4*)((char*)base + row * strideB + ((col0 * 2) ^ ((row & 7) << 4))) = v;
}
// per-wave scratch, fixed 64B stride (k_inner), XOR (row&3)<<4
__device__ __forceinline__ f16x8 scr_ld8(const half_t* base, int row, int k) {
    return *(const f16x8*)((const char*)base + row * 64 + ((k * 2) ^ ((row & 3) << 4)));
}
__device__ __forceinline__ void scr_st1(half_t* base, int row, int col, float v) {
    *(half_t*)((char*)base + row * 64 + ((col * 2) ^ ((row & 3) << 4))) = (half_t)v;
}
// per-wave scratch, parameterized stride (k_outer), XOR (row&3)<<4
__device__ __forceinline__ f16x8 scrS_ld8(const half_t* base, int row, int k, int strideB) {
    return *(const f16x8*)((const char*)base + row * strideB + ((k * 2) ^ ((row & 3) << 4)));
}
__device__ __forceinline__ void scrS_st1(half_t* base, int row, int col, int strideB, float v) {
    *(half_t*)((char*)base + row * strideB + ((col * 2) ^ ((row & 3) << 4))) = (half_t)v;
}

// ---------------------------------------------------------------------------
// k_pre: blocks 0..383 convert W1..W6 -> transposed f16; blocks 384..399 build
// dense outer adjacency Â_outer [16][128][128] f16 (row-major). [r4-proven]
// ---------------------------------------------------------------------------
__global__ __launch_bounds__(256) void k_pre(
    const float* __restrict__ W1, const float* __restrict__ W2,
    const float* __restrict__ W3, const float* __restrict__ W4,
    const float* __restrict__ W5, const float* __restrict__ W6,
    half_t* __restrict__ WT1, half_t* __restrict__ WT2,
    half_t* __restrict__ WT3, half_t* __restrict__ WT4,
    half_t* __restrict__ WT5, half_t* __restrict__ WT6,
    const float* __restrict__ ew, const int* __restrict__ esrc,
    const int* __restrict__ edst, half_t* __restrict__ Aout)
{
    __shared__ float Af[NPO * NPO];
    __shared__ int cO[NPO], cI[NPO];
    __shared__ float rso[NPO], rsi[NPO];
    const int t = threadIdx.x;

    if (blockIdx.x < 384) {
        int i = blockIdx.x * 256 + t;
        const float* src; half_t* dst; int K;
        if      (i < 8192)  { src = W1; dst = WT1; K = 64; }
        else if (i < 24576) { src = W2; dst = WT2; K = 128; i -= 8192; }
        else if (i < 49152) { src = W3; dst = WT3; K = 192; i -= 24576; }
        else if (i < 65536) { src = W4; dst = WT4; K = 128; i -= 49152; }
        else if (i < 81920) { src = W5; dst = WT5; K = 128; i -= 65536; }
        else                { src = W6; dst = WT6; K = 128; i -= 81920; }
        int c = i & 127, k = i >> 7;
        dst[c * K + k] = (half_t)src[k * 128 + c];
        return;
    }

    const int g = blockIdx.x - 384;
    const int nb = g * NPO, eb = g * EPO;
    for (int i = t; i < NPO * NPO; i += 256) Af[i] = 0.f;
    if (t < NPO) { cO[t] = 0; cI[t] = 0; }
    __syncthreads();
    for (int e = t; e < EPO; e += 256) {
        int s = esrc[eb + e] - nb, d = edst[eb + e] - nb;
        atomicAdd(&Af[d * NPO + s], ew[eb + e]);
        atomicAdd(&cO[s], 1); atomicAdd(&cI[d], 1);
    }
    __syncthreads();
    if (t < NPO) {
        rso[t] = rsqrtf((float)max(cO[t], 1));
        rsi[t] = rsqrtf((float)max(cI[t], 1));
    }
    __syncthreads();
    for (int i = t; i < 128 * 16; i += 256) {
        int d = i >> 4, s0 = (i & 15) * 8;
        f16x8 v;
        #pragma unroll
        for (int j = 0; j < 8; j++) {
            int s = s0 + j;
            float x = (d < NPO && s < NPO) ? Af[d * NPO + s] * rsi[d] * rso[s] : 0.f;
            v[j] = (half_t)x;
        }
        *(f16x8*)&Aout[(size_t)g * 16384 + d * 128 + s0] = v;
    }
}

// ---------------------------------------------------------------------------
// Inner fused [r15-proven verbatim, __launch_bounds__(256,5)]: unified
// VGPR+AGPR pressure is in (85,102] — (256,6)/(256,7) both spill (r16/r17).
// ---------------------------------------------------------------------------
__global__ __launch_bounds__(256, 5) void k_inner(
    const float* __restrict__ X, const float* __restrict__ outfeat,
    const float* __restrict__ ew, const int* __restrict__ esrc,
    const int* __restrict__ edst,
    const half_t* __restrict__ WT1, const float* __restrict__ b1,
    const half_t* __restrict__ WT2, const float* __restrict__ b2,
    half_t* __restrict__ merged)
{
    __shared__ alignas(16) char smem[21504];
    half_t* R2  = (half_t*)smem;             // [128][64] f16 swz s128 (h1T)
    float*  Af  = (float*)smem;              // [64][64] f32, bank-swizzled (alias)
    half_t* scr = (half_t*)(smem + 16384);   // [4 waves][16][32] f16
    float*  pool= (float*)(smem + 20480);    // [128]
    int*    cO  = (int*)(smem + 20992);      // [64]
    int*    cI  = (int*)(smem + 21248);      // [64]

    const int g = blockIdx.x, t = threadIdx.x;
    const int w = t >> 6, l = t & 63, lr = l & 15, lk = l >> 4;
    const int nb = g * NPI, eb = g * EPI;
    half_t* scrw = scr + w * 512;

    // ---- all global prefetches issued at kernel entry ----
    float ofv = (t < 64) ? outfeat[(size_t)g * 64 + t] : 0.f;
    int s0e, d0e; float w0e;
    { int e = eb + t; s0e = esrc[e] - nb; d0e = edst[e] - nb; w0e = ew[e]; }
    int s1e = 0, d1e = 0; float w1e = 0.f;
    const bool e1v = (t + 256 < EPI);
    if (e1v) { int e = eb + t + 256; s1e = esrc[e] - nb; d1e = edst[e] - nb; w1e = ew[e]; }
    // T1 B-fragments direct from X (L2-resident; pad killed by Â zero cols)
    f16x8 bx[8];
    #pragma unroll
    for (int fi = 0; fi < 4; fi++) {
        #pragma unroll
        for (int ks = 0; ks < 2; ks++) {
            f16x8 v;
            #pragma unroll
            for (int jj = 0; jj < 8; jj++) {
                int n = ks * 32 + lk * 8 + jj;
                int ridx = nb + n; if (ridx > N_IN - 1) ridx = N_IN - 1;
                v[jj] = (half_t)X[(size_t)ridx * 64 + fi * 16 + lr];
            }
            bx[fi * 2 + ks] = v;
        }
    }

    if (t < 64) { cO[t] = 0; cI[t] = 0; }
    if (t >= 64 && t < 192) pool[t - 64] = 0.f;
    {
        const f32x4 z4 = {0.f, 0.f, 0.f, 0.f};
        #pragma unroll
        for (int i = 0; i < 4; i++) *(f32x4*)&Af[(i * 256 + t) * 4] = z4;
    }
    lds_barrier();                                           // B1

    atomicAdd(&Af[d0e * 64 + (s0e ^ ((d0e & 7) << 2))], w0e);
    atomicAdd(&cO[s0e], 1); atomicAdd(&cI[d0e], 1);
    if (e1v) {
        atomicAdd(&Af[d1e * 64 + (s1e ^ ((d1e & 7) << 2))], w1e);
        atomicAdd(&cO[s1e], 1); atomicAdd(&cI[d1e], 1);
    }
    lds_barrier();                                           // B2

    f16x8 afr[2];
    {
        const int r = w * 16 + lr;
        const int sw = (r & 7) << 2;
        const float rsi_l = rsqrtf((float)max(cI[r], 1));
        #pragma unroll
        for (int ks = 0; ks < 2; ks++) {
            const int c0 = ks * 32 + lk * 8;
            f32x4 v0 = *(const f32x4*)&Af[r * 64 + (c0 ^ sw)];
            f32x4 v1 = *(const f32x4*)&Af[r * 64 + ((c0 + 4) ^ sw)];
            f16x8 fr;
            #pragma unroll
            for (int j = 0; j < 4; j++)
                fr[j] = (half_t)(v0[j] * rsi_l * rsqrtf((float)max(cO[c0 + j], 1)));
            #pragma unroll
            for (int j = 0; j < 4; j++)
                fr[4 + j] = (half_t)(v1[j] * rsi_l * rsqrtf((float)max(cO[c0 + 4 + j], 1)));
            afr[ks] = fr;
        }
    }
    lds_barrier();                                           // B3 (Af reads done)

    // ---- T1 = Â@X (strip-fused, B from registers) -> H1 = relu(T1@W1+b1) ----
    f32x4 hacc[8] = {};
    #pragma unroll
    for (int kf = 0; kf < 2; kf++) {
        f16x8 wb[8];
        #pragma unroll
        for (int nt = 0; nt < 8; nt++)
            wb[nt] = *(const f16x8*)&WT1[(nt * 16 + lr) * 64 + kf * 32 + lk * 8];
        #pragma unroll
        for (int j = 0; j < 2; j++) {
            const int ft = kf * 2 + j;
            f32x4 tacc = {};
            #pragma unroll
            for (int ks = 0; ks < 2; ks++)
                tacc = MFMA(afr[ks], bx[ft * 2 + ks], tacc);
            #pragma unroll
            for (int q = 0; q < 4; q++) scr_st1(scrw, lk * 4 + q, j * 16 + lr, tacc[q]);
        }
        f16x8 a1 = scr_ld8(scrw, lr, lk * 8);
        #pragma unroll
        for (int nt = 0; nt < 8; nt++) hacc[nt] = MFMA(a1, wb[nt], hacc[nt]);
    }
    #pragma unroll
    for (int nt = 0; nt < 8; nt++) {
        int c = nt * 16 + lr;
        float bb = b1[c];
        f16x4 hv;
        #pragma unroll
        for (int q = 0; q < 4; q++) hv[q] = (half_t)fmaxf(hacc[nt][q] + bb, 0.f);
        lds_st4h(R2, c, w * 16 + lk * 4, 128, hv);
    }
    lds_barrier();                                           // B4 (h1T visible)

    // ---- T2 = Â@h1 (strip-fused) -> H2 = relu(T2@W2+b2) -> masked pool ----
    f32x4 h2[8] = {};
    #pragma unroll
    for (int kf = 0; kf < 4; kf++) {
        f16x8 wb[8];
        #pragma unroll
        for (int nt = 0; nt < 8; nt++)
            wb[nt] = *(const f16x8*)&WT2[(nt * 16 + lr) * 128 + kf * 32 + lk * 8];
        #pragma unroll
        for (int j = 0; j < 2; j++) {
            const int ft = kf * 2 + j;
            f32x4 tacc = {};
            #pragma unroll
            for (int ks = 0; ks < 2; ks++) {
                f16x8 b = lds_ld8(R2, ft * 16 + lr, ks * 32 + lk * 8, 128);
                tacc = MFMA(afr[ks], b, tacc);
            }
            #pragma unroll
            for (int q = 0; q < 4; q++) scr_st1(scrw, lk * 4 + q, j * 16 + lr, tacc[q]);
        }
        f16x8 a1 = scr_ld8(scrw, lr, lk * 8);
        #pragma unroll
        for (int nt = 0; nt < 8; nt++) h2[nt] = MFMA(a1, wb[nt], h2[nt]);
    }
    #pragma unroll
    for (int nt = 0; nt < 8; nt++) {
        int c = nt * 16 + lr;
        float bb = b2[c];
        float ps = 0.f;
        #pragma unroll
        for (int q = 0; q < 4; q++) {
            int m = w * 16 + lk * 4 + q;
            float v = fmaxf(h2[nt][q] + bb, 0.f);
            ps += (m < NPI) ? v : 0.f;
        }
        ps += __shfl_xor(ps, 16);
        ps += __shfl_xor(ps, 32);
        if (lk == 0) atomicAdd(&pool[c], ps);
    }
    lds_barrier();                                           // B5
    if (t < 64) merged[(size_t)g * 192 + t] = (half_t)ofv;
    else if (t < 192) merged[(size_t)g * 192 + t] = (half_t)(pool[t - 64] * (1.f / NPI));
}

// ---------------------------------------------------------------------------
// k_outer, strip-fused (k_inner's proven T->scr->H pattern): 512 thr = 8
// waves x 16 node-rows. Per layer: [stage bufP] -> per-wave T over ALL FIN
// cols into private scr -> H from scr with WT pipelining under T (no barrier
// between T and H!) -> write bufP. 2 barriers/layer vs ~26 in the old shape.
// ---------------------------------------------------------------------------
template <int FIN, bool STAGE, bool LAST>
__device__ __forceinline__ void olayer(
    const f16x8* afr, const half_t* __restrict__ mg,
    const half_t* __restrict__ WT, const float* __restrict__ bias,
    half_t* bufP, half_t* scrw, float* pool,
    int w, int lr, int lk, int t)
{
    constexpr int SSTR = FIN * 2 + 16;   // padded scr stride: spreads banks
    if constexpr (STAGE) {
        const int s = t & 127, ch = t >> 7;
        #pragma unroll
        for (int j = 0; j < 6; j++) {
            int f0 = ch * 48 + j * 8;
            f16x8 hv = {};
            if (s < NPO) hv = *(const f16x8*)&mg[(size_t)s * 192 + f0];
            #pragma unroll
            for (int i = 0; i < 8; i++) lds_st1h(bufP, f0 + i, s, 256, hv[i]);
        }
        lds_barrier();
    }
    // T-phase: this wave's 16 rows x all FIN cols -> private scr
    #pragma unroll
    for (int ft = 0; ft < FIN / 16; ft++) {
        f32x4 tacc = {};
        #pragma unroll
        for (int ks = 0; ks < 4; ks++) {
            f16x8 b = lds_ld8(bufP, ft * 16 + lr, ks * 32 + lk * 8, 256);
            tacc = MFMA(afr[ks], b, tacc);
        }
        #pragma unroll
        for (int q = 0; q < 4; q++)
            scrS_st1(scrw, lk * 4 + q, ft * 16 + lr, SSTR, tacc[q]);
    }
    // H-phase: wave-local, no barrier — WT loads pipeline under T
    f32x4 hacc[8] = {};
    #pragma unroll
    for (int kf = 0; kf < FIN / 32; kf++) {
        f16x8 a1 = scrS_ld8(scrw, lr, kf * 32 + lk * 8, SSTR);
        #pragma unroll
        for (int nt = 0; nt < 8; nt++) {
            f16x8 wb = *(const f16x8*)&WT[(size_t)(nt * 16 + lr) * FIN + kf * 32 + lk * 8];
            hacc[nt] = MFMA(a1, wb, hacc[nt]);
        }
    }
    lds_barrier();   // all waves' bufP reads complete before overwrite
    if constexpr (!LAST) {
        #pragma unroll
        for (int nt = 0; nt < 8; nt++) {
            int c = nt * 16 + lr;
            float bb = bias[c];
            #pragma unroll
            for (int q = 0; q < 4; q++)
                lds_st1(bufP, c, w * 16 + lk * 4 + q, 256, fmaxf(hacc[nt][q] + bb, 0.f));
        }
        lds_barrier();
    } else {
        #pragma unroll
        for (int nt = 0; nt < 8; nt++) {
            int c = nt * 16 + lr;
            float bb = bias[c];
            float ps = 0.f;
            #pragma unroll
            for (int q = 0; q < 4; q++) {
                int d = w * 16 + lk * 4 + q;
                float v = fmaxf(hacc[nt][q] + bb, 0.f);
                ps += (d < NPO) ? v : 0.f;
            }
            ps += __shfl_xor(ps, 16);
            ps += __shfl_xor(ps, 32);
            if (lk == 0) atomicAdd(&pool[c], ps);
        }
        lds_barrier();
    }
}

__global__ __launch_bounds__(512) void k_outer(
    const half_t* __restrict__ Aout, const half_t* __restrict__ merged,
    const half_t* __restrict__ WT3, const float* __restrict__ b3,
    const half_t* __restrict__ WT4, const float* __restrict__ b4,
    const half_t* __restrict__ WT5, const float* __restrict__ b5,
    const half_t* __restrict__ WT6, const float* __restrict__ b6,
    const float* __restrict__ Wc, const float* __restrict__ bc,
    float* __restrict__ out)
{
    __shared__ alignas(16) char smem[100928];
    half_t* bufP = (half_t*)smem;              // [192][256B] swz, 49152B
    // per-wave scr: 16 rows x 400B = 6400B per wave, 8 waves = 51200B
    float*  pool = (float*)(smem + 100352);    // [128]
    float*  cls  = (float*)(smem + 100864);    // [10]

    const int g = blockIdx.x, t = threadIdx.x;
    const int w = t >> 6, l = t & 63, lr = l & 15, lk = l >> 4;
    half_t* scrw = (half_t*)(smem + 49152 + w * 6400);
    const half_t* mg = merged + (size_t)g * NPO * 192;

    f16x8 afr[4];
    #pragma unroll
    for (int ks = 0; ks < 4; ks++)
        afr[ks] = *(const f16x8*)&Aout[(size_t)g * 16384
                                       + (w * 16 + lr) * 128 + ks * 32 + lk * 8];
    if (t < 128) pool[t] = 0.f;
    if (t >= 128 && t < 128 + NC) cls[t - 128] = 0.f;
    lds_barrier();

    olayer<192, true,  false>(afr, mg, WT3, b3, bufP, scrw, pool, w, lr, lk, t);
    olayer<128, false, false>(afr, nullptr, WT4, b4, bufP, scrw, pool, w, lr, lk, t);
    olayer<128, false, false>(afr, nullptr, WT5, b5, bufP, scrw, pool, w, lr, lk, t);
    olayer<128, false, true >(afr, nullptr, WT6, b6, bufP, scrw, pool, w, lr, lk, t);

    if (t < 128) {
        float val = pool[t] * (1.f / NPO);
        float p[NC];
        #pragma unroll
        for (int c = 0; c < NC; c++) p[c] = val * Wc[t * NC + c];
        #pragma unroll
        for (int off = 32; off >= 1; off >>= 1)
            #pragma unroll
            for (int c = 0; c < NC; c++) p[c] += __shfl_xor(p[c], off);
        if ((t & 63) == 0)
            #pragma unroll
            for (int c = 0; c < NC; c++) atomicAdd(&cls[c], p[c]);
    }
    lds_barrier();
    if (t < NC) out[g * NC + t] = cls[t] + bc[t];
}

extern "C" void kernel_launch(void* const* d_in, const int* in_sizes, int n_in,
                              void* d_out, int out_size, void* d_ws, size_t ws_size,
                              hipStream_t stream)
{
    const float* X       = (const float*)d_in[0];
    const float* outfeat = (const float*)d_in[1];
    const float* iew     = (const float*)d_in[2];
    const float* oew     = (const float*)d_in[3];
    const float* W1 = (const float*)d_in[4];  const float* b1 = (const float*)d_in[5];
    const float* W2 = (const float*)d_in[6];  const float* b2 = (const float*)d_in[7];
    const float* W3 = (const float*)d_in[8];  const float* b3 = (const float*)d_in[9];
    const float* W4 = (const float*)d_in[10]; const float* b4 = (const float*)d_in[11];
    const float* W5 = (const float*)d_in[12]; const float* b5 = (const float*)d_in[13];
    const float* W6 = (const float*)d_in[14]; const float* b6 = (const float*)d_in[15];
    const float* Wc = (const float*)d_in[16]; const float* bc = (const float*)d_in[17];
    const int* isrc = (const int*)d_in[18];   const int* idst = (const int*)d_in[19];
    const int* osrc = (const int*)d_in[20];   const int* odst = (const int*)d_in[21];

    char* base = (char*)d_ws;
    half_t* WT1 = (half_t*)(base + 0);        // [128][64]
    half_t* WT2 = (half_t*)(base + 16384);    // [128][128]
    half_t* WT3 = (half_t*)(base + 49152);    // [128][192]
    half_t* WT4 = (half_t*)(base + 98304);    // [128][128]
    half_t* WT5 = (half_t*)(base + 131072);   // [128][128]
    half_t* WT6 = (half_t*)(base + 163840);   // [128][128]
    half_t* AoutG  = (half_t*)(base + 196608);   // [16][128][128]
    half_t* merged = (half_t*)(base + 720896);   // [2000][192]

    k_pre<<<400, 256, 0, stream>>>(W1, W2, W3, W4, W5, W6,
                                   WT1, WT2, WT3, WT4, WT5, WT6,
                                   oew, osrc, odst, AoutG);
    k_inner<<<N_OUT, 256, 0, stream>>>(X, outfeat, iew, isrc, idst,
                                       WT1, b1, WT2, b2, merged);
    k_outer<<<NB, 512, 0, stream>>>(AoutG, merged, WT3, b3, WT4, b4,
                                    WT5, b5, WT6, b6, Wc, bc, (float*)d_out);
}

// Round 19
// 115.892 us; speedup vs baseline: 1.2849x; 1.0383x over previous
//
#include <hip/hip_runtime.h>

#define NPI 50      // nodes per inner graph
#define EPI 400     // edges per inner graph
#define NPO 125     // nodes per outer graph
#define EPO 1000    // edges per outer graph
#define N_IN 100000
#define N_OUT 2000
#define NB 16       // batch graphs
#define NC 10

typedef _Float16 half_t;
typedef _Float16 f16x8 __attribute__((ext_vector_type(8)));
typedef _Float16 f16x4 __attribute__((ext_vector_type(4)));
typedef float f32x4 __attribute__((ext_vector_type(4)));

#define MFMA(a, b, c) __builtin_amdgcn_mfma_f32_16x16x32_f16(a, b, c, 0, 0, 0)

// LDS-only barrier (r12-proven neutral vs __syncthreads, keeps prefetches live).
__device__ __forceinline__ void lds_barrier() {
    asm volatile("s_waitcnt lgkmcnt(0)" ::: "memory");
    __builtin_amdgcn_s_barrier();
}

// Swizzled LDS helpers. XOR of (row&7) into byte bits 4..6 keeps ds_read_b128
// conflict-free when 16 lanes read 16 consecutive rows.
__device__ __forceinline__ f16x8 lds_ld8(const half_t* base, int row, int k, int strideB) {
    return *(const f16x8*)((const char*)base + row * strideB + ((k * 2) ^ ((row & 7) << 4)));
}
__device__ __forceinline__ void lds_st1(half_t* base, int row, int col, int strideB, float v) {
    *(half_t*)((char*)base + row * strideB + ((col * 2) ^ ((row & 7) << 4))) = (half_t)v;
}
__device__ __forceinline__ void lds_st1h(half_t* base, int row, int col, int strideB, half_t v) {
    *(half_t*)((char*)base + row * strideB + ((col * 2) ^ ((row & 7) << 4))) = v;
}
// b64 store of 4 node-contiguous halfs (col0 multiple of 4): 8B span stays
// contiguous under the XOR-bits-4..6 swizzle.
__device__ __forceinline__ void lds_st4h(half_t* base, int row, int col0, int strideB, f16x4 v) {
    *(f16x4*)((char*)base + row * strideB + ((col0 * 2) ^ ((row & 7) << 4))) = v;
}
// per-wave scratch [16][32] f16, stride 64B, XOR (row&3)<<4
__device__ __forceinline__ f16x8 scr_ld8(const half_t* base, int row, int k) {
    return *(const f16x8*)((const char*)base + row * 64 + ((k * 2) ^ ((row & 3) << 4)));
}
__device__ __forceinline__ void scr_st1(half_t* base, int row, int col, float v) {
    *(half_t*)((char*)base + row * 64 + ((col * 2) ^ ((row & 3) << 4))) = (half_t)v;
}

// ---------------------------------------------------------------------------
// k_pre: blocks 0..383 convert W1..W6 -> transposed f16; blocks 384..399 build
// dense outer adjacency Â_outer [16][128][128] f16 (row-major). [r4-proven]
// ---------------------------------------------------------------------------
__global__ __launch_bounds__(256) void k_pre(
    const float* __restrict__ W1, const float* __restrict__ W2,
    const float* __restrict__ W3, const float* __restrict__ W4,
    const float* __restrict__ W5, const float* __restrict__ W6,
    half_t* __restrict__ WT1, half_t* __restrict__ WT2,
    half_t* __restrict__ WT3, half_t* __restrict__ WT4,
    half_t* __restrict__ WT5, half_t* __restrict__ WT6,
    const float* __restrict__ ew, const int* __restrict__ esrc,
    const int* __restrict__ edst, half_t* __restrict__ Aout)
{
    __shared__ float Af[NPO * NPO];
    __shared__ int cO[NPO], cI[NPO];
    __shared__ float rso[NPO], rsi[NPO];
    const int t = threadIdx.x;

    if (blockIdx.x < 384) {
        int i = blockIdx.x * 256 + t;
        const float* src; half_t* dst; int K;
        if      (i < 8192)  { src = W1; dst = WT1; K = 64; }
        else if (i < 24576) { src = W2; dst = WT2; K = 128; i -= 8192; }
        else if (i < 49152) { src = W3; dst = WT3; K = 192; i -= 24576; }
        else if (i < 65536) { src = W4; dst = WT4; K = 128; i -= 49152; }
        else if (i < 81920) { src = W5; dst = WT5; K = 128; i -= 65536; }
        else                { src = W6; dst = WT6; K = 128; i -= 81920; }
        int c = i & 127, k = i >> 7;
        dst[c * K + k] = (half_t)src[k * 128 + c];
        return;
    }

    const int g = blockIdx.x - 384;
    const int nb = g * NPO, eb = g * EPO;
    for (int i = t; i < NPO * NPO; i += 256) Af[i] = 0.f;
    if (t < NPO) { cO[t] = 0; cI[t] = 0; }
    __syncthreads();
    for (int e = t; e < EPO; e += 256) {
        int s = esrc[eb + e] - nb, d = edst[eb + e] - nb;
        atomicAdd(&Af[d * NPO + s], ew[eb + e]);
        atomicAdd(&cO[s], 1); atomicAdd(&cI[d], 1);
    }
    __syncthreads();
    if (t < NPO) {
        rso[t] = rsqrtf((float)max(cO[t], 1));
        rsi[t] = rsqrtf((float)max(cI[t], 1));
    }
    __syncthreads();
    for (int i = t; i < 128 * 16; i += 256) {
        int d = i >> 4, s0 = (i & 15) * 8;
        f16x8 v;
        #pragma unroll
        for (int j = 0; j < 8; j++) {
            int s = s0 + j;
            float x = (d < NPO && s < NPO) ? Af[d * NPO + s] * rsi[d] * rso[s] : 0.f;
            v[j] = (half_t)x;
        }
        *(f16x8*)&Aout[(size_t)g * 16384 + d * 128 + s0] = v;
    }
}

// ---------------------------------------------------------------------------
// Inner fused [r15-proven verbatim, __launch_bounds__(256,5)]: unified
// VGPR+AGPR pressure is in (85,102] — (256,6)/(256,7) both spill (r16/r17).
// ---------------------------------------------------------------------------
__global__ __launch_bounds__(256, 5) void k_inner(
    const float* __restrict__ X, const float* __restrict__ outfeat,
    const float* __restrict__ ew, const int* __restrict__ esrc,
    const int* __restrict__ edst,
    const half_t* __restrict__ WT1, const float* __restrict__ b1,
    const half_t* __restrict__ WT2, const float* __restrict__ b2,
    half_t* __restrict__ merged)
{
    __shared__ alignas(16) char smem[21504];
    half_t* R2  = (half_t*)smem;             // [128][64] f16 swz s128 (h1T)
    float*  Af  = (float*)smem;              // [64][64] f32, bank-swizzled (alias)
    half_t* scr = (half_t*)(smem + 16384);   // [4 waves][16][32] f16
    float*  pool= (float*)(smem + 20480);    // [128]
    int*    cO  = (int*)(smem + 20992);      // [64]
    int*    cI  = (int*)(smem + 21248);      // [64]

    const int g = blockIdx.x, t = threadIdx.x;
    const int w = t >> 6, l = t & 63, lr = l & 15, lk = l >> 4;
    const int nb = g * NPI, eb = g * EPI;
    half_t* scrw = scr + w * 512;

    // ---- all global prefetches issued at kernel entry ----
    float ofv = (t < 64) ? outfeat[(size_t)g * 64 + t] : 0.f;
    int s0e, d0e; float w0e;
    { int e = eb + t; s0e = esrc[e] - nb; d0e = edst[e] - nb; w0e = ew[e]; }
    int s1e = 0, d1e = 0; float w1e = 0.f;
    const bool e1v = (t + 256 < EPI);
    if (e1v) { int e = eb + t + 256; s1e = esrc[e] - nb; d1e = edst[e] - nb; w1e = ew[e]; }
    // T1 B-fragments direct from X (L2-resident; pad killed by Â zero cols)
    f16x8 bx[8];
    #pragma unroll
    for (int fi = 0; fi < 4; fi++) {
        #pragma unroll
        for (int ks = 0; ks < 2; ks++) {
            f16x8 v;
            #pragma unroll
            for (int jj = 0; jj < 8; jj++) {
                int n = ks * 32 + lk * 8 + jj;
                int ridx = nb + n; if (ridx > N_IN - 1) ridx = N_IN - 1;
                v[jj] = (half_t)X[(size_t)ridx * 64 + fi * 16 + lr];
            }
            bx[fi * 2 + ks] = v;
        }
    }

    if (t < 64) { cO[t] = 0; cI[t] = 0; }
    if (t >= 64 && t < 192) pool[t - 64] = 0.f;
    {
        const f32x4 z4 = {0.f, 0.f, 0.f, 0.f};
        #pragma unroll
        for (int i = 0; i < 4; i++) *(f32x4*)&Af[(i * 256 + t) * 4] = z4;
    }
    lds_barrier();                                           // B1

    // edge scatter into bank-swizzled Af: element (d,s) at d*64 + (s^((d&7)<<2))
    atomicAdd(&Af[d0e * 64 + (s0e ^ ((d0e & 7) << 2))], w0e);
    atomicAdd(&cO[s0e], 1); atomicAdd(&cI[d0e], 1);
    if (e1v) {
        atomicAdd(&Af[d1e * 64 + (s1e ^ ((d1e & 7) << 2))], w1e);
        atomicAdd(&cO[s1e], 1); atomicAdd(&cI[d1e], 1);
    }
    lds_barrier();                                           // B2

    // ---- build Â A-fragments in registers: row = w*16+lr, ks in {0,1} ----
    f16x8 afr[2];
    {
        const int r = w * 16 + lr;
        const int sw = (r & 7) << 2;
        const float rsi_l = rsqrtf((float)max(cI[r], 1));
        #pragma unroll
        for (int ks = 0; ks < 2; ks++) {
            const int c0 = ks * 32 + lk * 8;
            f32x4 v0 = *(const f32x4*)&Af[r * 64 + (c0 ^ sw)];
            f32x4 v1 = *(const f32x4*)&Af[r * 64 + ((c0 + 4) ^ sw)];
            f16x8 fr;
            #pragma unroll
            for (int j = 0; j < 4; j++)
                fr[j] = (half_t)(v0[j] * rsi_l * rsqrtf((float)max(cO[c0 + j], 1)));
            #pragma unroll
            for (int j = 0; j < 4; j++)
                fr[4 + j] = (half_t)(v1[j] * rsi_l * rsqrtf((float)max(cO[c0 + 4 + j], 1)));
            afr[ks] = fr;
        }
    }
    lds_barrier();                                           // B3 (Af reads done)

    // ---- T1 = Â@X (strip-fused, B from registers) -> H1 = relu(T1@W1+b1) ----
    f32x4 hacc[8] = {};
    #pragma unroll
    for (int kf = 0; kf < 2; kf++) {
        f16x8 wb[8];
        #pragma unroll
        for (int nt = 0; nt < 8; nt++)
            wb[nt] = *(const f16x8*)&WT1[(nt * 16 + lr) * 64 + kf * 32 + lk * 8];
        #pragma unroll
        for (int j = 0; j < 2; j++) {
            const int ft = kf * 2 + j;
            f32x4 tacc = {};
            #pragma unroll
            for (int ks = 0; ks < 2; ks++)
                tacc = MFMA(afr[ks], bx[ft * 2 + ks], tacc);
            #pragma unroll
            for (int q = 0; q < 4; q++) scr_st1(scrw, lk * 4 + q, j * 16 + lr, tacc[q]);
        }
        f16x8 a1 = scr_ld8(scrw, lr, lk * 8);
        #pragma unroll
        for (int nt = 0; nt < 8; nt++) hacc[nt] = MFMA(a1, wb[nt], hacc[nt]);
    }
    // h1T writeback: b64 (4 node-contiguous halfs per store)
    #pragma unroll
    for (int nt = 0; nt < 8; nt++) {
        int c = nt * 16 + lr;
        float bb = b1[c];
        f16x4 hv;
        #pragma unroll
        for (int q = 0; q < 4; q++) hv[q] = (half_t)fmaxf(hacc[nt][q] + bb, 0.f);
        lds_st4h(R2, c, w * 16 + lk * 4, 128, hv);
    }
    lds_barrier();                                           // B4 (h1T visible)

    // ---- T2 = Â@h1 (strip-fused) -> H2 = relu(T2@W2+b2) -> masked pool ----
    f32x4 h2[8] = {};
    #pragma unroll
    for (int kf = 0; kf < 4; kf++) {
        f16x8 wb[8];
        #pragma unroll
        for (int nt = 0; nt < 8; nt++)
            wb[nt] = *(const f16x8*)&WT2[(nt * 16 + lr) * 128 + kf * 32 + lk * 8];
        #pragma unroll
        for (int j = 0; j < 2; j++) {
            const int ft = kf * 2 + j;
            f32x4 tacc = {};
            #pragma unroll
            for (int ks = 0; ks < 2; ks++) {
                f16x8 b = lds_ld8(R2, ft * 16 + lr, ks * 32 + lk * 8, 128);
                tacc = MFMA(afr[ks], b, tacc);
            }
            #pragma unroll
            for (int q = 0; q < 4; q++) scr_st1(scrw, lk * 4 + q, j * 16 + lr, tacc[q]);
        }
        f16x8 a1 = scr_ld8(scrw, lr, lk * 8);
        #pragma unroll
        for (int nt = 0; nt < 8; nt++) h2[nt] = MFMA(a1, wb[nt], h2[nt]);
    }
    #pragma unroll
    for (int nt = 0; nt < 8; nt++) {
        int c = nt * 16 + lr;
        float bb = b2[c];
        float ps = 0.f;
        #pragma unroll
        for (int q = 0; q < 4; q++) {
            int m = w * 16 + lk * 4 + q;
            float v = fmaxf(h2[nt][q] + bb, 0.f);
            ps += (m < NPI) ? v : 0.f;
        }
        ps += __shfl_xor(ps, 16);
        ps += __shfl_xor(ps, 32);
        if (lk == 0) atomicAdd(&pool[c], ps);
    }
    lds_barrier();                                           // B5
    if (t < 64) merged[(size_t)g * 192 + t] = (half_t)ofv;
    else if (t < 192) merged[(size_t)g * 192 + t] = (half_t)(pool[t - 64] * (1.f / NPI));
}

// ---------------------------------------------------------------------------
// Outer fused @1024 threads [r9/r15-proven]: Â in registers, WT register-
// prefetch, early stage loads, parallel classifier.
// ---------------------------------------------------------------------------
template <int FIN, bool STAGE, bool LAST>
__device__ __forceinline__ void outer_layer(
    const f16x8* afr, const half_t* __restrict__ mg,
    const half_t* __restrict__ WT, const float* __restrict__ bias,
    half_t* bufP, half_t* bufQ, float* pool,
    int wr, int wc, int lr, int lk, int t)
{
    f32x4 hacc[4] = {};
    constexpr int NCH = FIN / 64;
    f16x8 hv[NCH];
    if constexpr (STAGE) {
        const int s = t >> 3, fo = (t & 7) * 8;
        #pragma unroll
        for (int ch = 0; ch < NCH; ch++) {
            f16x8 z = {};
            hv[ch] = (s < NPO) ? *(const f16x8*)&mg[(size_t)s * 192 + ch * 64 + fo] : z;
        }
    }
    #pragma unroll
    for (int ch = 0; ch < NCH; ch++) {
        f16x8 wtb[8];
        #pragma unroll
        for (int ks2 = 0; ks2 < 2; ks2++)
            #pragma unroll
            for (int nt = 0; nt < 4; nt++)
                wtb[ks2 * 4 + nt] = *(const f16x8*)&WT[
                    (size_t)(wc * 64 + nt * 16 + lr) * FIN + ch * 64 + ks2 * 32 + lk * 8];
        if constexpr (STAGE) {
            const int s = t >> 3, fo = (t & 7) * 8;
            #pragma unroll
            for (int j = 0; j < 8; j++) lds_st1h(bufP, fo + j, s, 256, hv[ch][j]);
            lds_barrier();
        }
        const int rb = STAGE ? 0 : ch * 64;
        f32x4 tacc[2] = {};
        #pragma unroll
        for (int ks = 0; ks < 4; ks++) {
            #pragma unroll
            for (int nt = 0; nt < 2; nt++) {
                f16x8 b = lds_ld8(bufP, rb + wc * 32 + nt * 16 + lr, ks * 32 + lk * 8, 256);
                tacc[nt] = MFMA(afr[ks], b, tacc[nt]);
            }
        }
        #pragma unroll
        for (int nt = 0; nt < 2; nt++)
            #pragma unroll
            for (int q = 0; q < 4; q++)
                lds_st1(bufQ, wr * 16 + lk * 4 + q, wc * 32 + nt * 16 + lr, 128,
                        tacc[nt][q]);
        lds_barrier();
        #pragma unroll
        for (int ks2 = 0; ks2 < 2; ks2++) {
            f16x8 a1 = lds_ld8(bufQ, wr * 16 + lr, ks2 * 32 + lk * 8, 128);
            #pragma unroll
            for (int nt = 0; nt < 4; nt++)
                hacc[nt] = MFMA(a1, wtb[ks2 * 4 + nt], hacc[nt]);
        }
        lds_barrier();
    }
    if constexpr (!LAST) {
        #pragma unroll
        for (int nt = 0; nt < 4; nt++) {
            int c = wc * 64 + nt * 16 + lr;
            float bb = bias[c];
            #pragma unroll
            for (int q = 0; q < 4; q++)
                lds_st1(bufP, c, wr * 16 + lk * 4 + q, 256, fmaxf(hacc[nt][q] + bb, 0.f));
        }
        lds_barrier();
    } else {
        #pragma unroll
        for (int nt = 0; nt < 4; nt++) {
            int c = wc * 64 + nt * 16 + lr;
            float bb = bias[c];
            float ps = 0.f;
            #pragma unroll
            for (int q = 0; q < 4; q++) {
                int d = wr * 16 + lk * 4 + q;
                float v = fmaxf(hacc[nt][q] + bb, 0.f);
                ps += (d < NPO) ? v : 0.f;
            }
            ps += __shfl_xor(ps, 16);
            ps += __shfl_xor(ps, 32);
            if (lk == 0) atomicAdd(&pool[c], ps);
        }
        lds_barrier();
    }
}

__global__ __launch_bounds__(1024) void k_outer(
    const half_t* __restrict__ Aout, const half_t* __restrict__ merged,
    const half_t* __restrict__ WT3, const float* __restrict__ b3,
    const half_t* __restrict__ WT4, const float* __restrict__ b4,
    const half_t* __restrict__ WT5, const float* __restrict__ b5,
    const half_t* __restrict__ WT6, const float* __restrict__ b6,
    const float* __restrict__ Wc, const float* __restrict__ bc,
    float* __restrict__ out)
{
    __shared__ alignas(16) char smem[49704];
    half_t* bufP = (half_t*)smem;             // [128][256B] swz (h^T)
    half_t* bufQ = (half_t*)(smem + 32768);   // [128][128B] swz (T chunk)
    float*  pool = (float*)(smem + 49152);    // [128]
    float*  cls  = (float*)(smem + 49664);    // [10]

    const int g = blockIdx.x, t = threadIdx.x;
    const int w = t >> 6, l = t & 63, lr = l & 15, lk = l >> 4;
    const int wr = w & 7, wc = w >> 3;
    const half_t* mg = merged + (size_t)g * NPO * 192;

    f16x8 afr[4];
    #pragma unroll
    for (int ks = 0; ks < 4; ks++)
        afr[ks] = *(const f16x8*)&Aout[(size_t)g * 16384
                                       + (wr * 16 + lr) * 128 + ks * 32 + lk * 8];
    if (t < 128) pool[t] = 0.f;
    if (t >= 128 && t < 128 + NC) cls[t - 128] = 0.f;
    lds_barrier();

    outer_layer<192, true,  false>(afr, mg, WT3, b3, bufP, bufQ, pool, wr, wc, lr, lk, t);
    outer_layer<128, false, false>(afr, nullptr, WT4, b4, bufP, bufQ, pool, wr, wc, lr, lk, t);
    outer_layer<128, false, false>(afr, nullptr, WT5, b5, bufP, bufQ, pool, wr, wc, lr, lk, t);
    outer_layer<128, false, true >(afr, nullptr, WT6, b6, bufP, bufQ, pool, wr, wc, lr, lk, t);

    if (t < 128) {
        float val = pool[t] * (1.f / NPO);
        float p[NC];
        #pragma unroll
        for (int c = 0; c < NC; c++) p[c] = val * Wc[t * NC + c];
        #pragma unroll
        for (int off = 32; off >= 1; off >>= 1)
            #pragma unroll
            for (int c = 0; c < NC; c++) p[c] += __shfl_xor(p[c], off);
        if ((t & 63) == 0)
            #pragma unroll
            for (int c = 0; c < NC; c++) atomicAdd(&cls[c], p[c]);
    }
    lds_barrier();
    if (t < NC) out[g * NC + t] = cls[t] + bc[t];
}

extern "C" void kernel_launch(void* const* d_in, const int* in_sizes, int n_in,
                              void* d_out, int out_size, void* d_ws, size_t ws_size,
                              hipStream_t stream)
{
    const float* X       = (const float*)d_in[0];
    const float* outfeat = (const float*)d_in[1];
    const float* iew     = (const float*)d_in[2];
    const float* oew     = (const float*)d_in[3];
    const float* W1 = (const float*)d_in[4];  const float* b1 = (const float*)d_in[5];
    const float* W2 = (const float*)d_in[6];  const float* b2 = (const float*)d_in[7];
    const float* W3 = (const float*)d_in[8];  const float* b3 = (const float*)d_in[9];
    const float* W4 = (const float*)d_in[10]; const float* b4 = (const float*)d_in[11];
    const float* W5 = (const float*)d_in[12]; const float* b5 = (const float*)d_in[13];
    const float* W6 = (const float*)d_in[14]; const float* b6 = (const float*)d_in[15];
    const float* Wc = (const float*)d_in[16]; const float* bc = (const float*)d_in[17];
    const int* isrc = (const int*)d_in[18];   const int* idst = (const int*)d_in[19];
    const int* osrc = (const int*)d_in[20];   const int* odst = (const int*)d_in[21];

    char* base = (char*)d_ws;
    half_t* WT1 = (half_t*)(base + 0);        // [128][64]
    half_t* WT2 = (half_t*)(base + 16384);    // [128][128]
    half_t* WT3 = (half_t*)(base + 49152);    // [128][192]
    half_t* WT4 = (half_t*)(base + 98304);    // [128][128]
    half_t* WT5 = (half_t*)(base + 131072);   // [128][128]
    half_t* WT6 = (half_t*)(base + 163840);   // [128][128]
    half_t* AoutG  = (half_t*)(base + 196608);   // [16][128][128]
    half_t* merged = (half_t*)(base + 720896);   // [2000][192]

    k_pre<<<400, 256, 0, stream>>>(W1, W2, W3, W4, W5, W6,
                                   WT1, WT2, WT3, WT4, WT5, WT6,
                                   oew, osrc, odst, AoutG);
    k_inner<<<N_OUT, 256, 0, stream>>>(X, outfeat, iew, isrc, idst,
                                       WT1, b1, WT2, b2, merged);
    k_outer<<<NB, 1024, 0, stream>>>(AoutG, merged, WT3, b3, WT4, b4,
                                     WT5, b5, WT6, b6, Wc, bc, (float*)d_out);
}